// Round 1
// baseline (1361.750 us; speedup 1.0000x reference)
//
#include <hip/hip_runtime.h>
#include <hip/hip_bf16.h>
#include <math.h>

// ---------------- constants ----------------
// x,y: (4, 64, 256, 256) fp32. NCHW. plane = 65536 px, image = 64 planes.
#define NPX   65536          // 256*256
#define NPP   16384          // 128*128
#define IMGST 4194304        // 64*65536
#define NB    4

__device__ __forceinline__ float wave_sum(float v) {
#pragma unroll
    for (int off = 32; off >= 1; off >>= 1) v += __shfl_xor(v, off, 64);
    return v;
}

// ---------------- K1: depthwise conv (one input -> one output) ----------------
// grid (64 tiles, 256 b*c), block 256. 32x32 tile, halo 3 (max kernel 7).
__global__ __launch_bounds__(256) void dsattn_dwconv(
        const float* __restrict__ in, float* __restrict__ outp,
        const float* __restrict__ w3, const float* __restrict__ w5,
        const float* __restrict__ w7) {
    __shared__ float sm[38 * 38];
    __shared__ float wsm[49];
    const int tid = threadIdx.x;
    const int tile = blockIdx.x;
    const int tx = tile & 7, ty = tile >> 3;
    const int bc = blockIdx.y;            // b*64 + c
    const int c = bc & 63;
    const float* plane = in + (size_t)bc * NPX;
    const int row0 = ty * 32 - 3, col0 = tx * 32 - 3;

    for (int idx = tid; idx < 38 * 38; idx += 256) {
        int r = idx / 38, cc = idx - r * 38;
        int gr = row0 + r, gc = col0 + cc;
        float v = 0.f;
        if ((unsigned)gr < 256u && (unsigned)gc < 256u) v = plane[gr * 256 + gc];
        sm[idx] = v;
    }
    int k; const float* wp;
    if (c < 32)      { k = 3; wp = w3 + c * 9; }
    else if (c < 48) { k = 5; wp = w5 + (c - 32) * 25; }
    else             { k = 7; wp = w7 + (c - 48) * 49; }
    if (tid < k * k) wsm[tid] = wp[tid];
    __syncthreads();

    const int lx = tid & 31, ly0 = tid >> 5;
    float* oplane = outp + (size_t)bc * NPX;
#pragma unroll
    for (int rr = 0; rr < 4; ++rr) {
        const int ly = ly0 + rr * 8;
        float acc = 0.f;
        if (k == 3) {
#pragma unroll
            for (int dy = 0; dy < 3; ++dy)
#pragma unroll
                for (int dx = 0; dx < 3; ++dx)
                    acc = fmaf(wsm[dy * 3 + dx], sm[(ly + 2 + dy) * 38 + lx + 2 + dx], acc);
        } else if (k == 5) {
#pragma unroll
            for (int dy = 0; dy < 5; ++dy)
#pragma unroll
                for (int dx = 0; dx < 5; ++dx)
                    acc = fmaf(wsm[dy * 5 + dx], sm[(ly + 1 + dy) * 38 + lx + 1 + dx], acc);
        } else {
#pragma unroll
            for (int dy = 0; dy < 7; ++dy)
#pragma unroll
                for (int dx = 0; dx < 7; ++dx)
                    acc = fmaf(wsm[dy * 7 + dx], sm[(ly + dy) * 38 + lx + dx], acc);
        }
        oplane[(ty * 32 + ly) * 256 + tx * 32 + lx] = acc;
    }
}

// ---------------- K2: pooled[b][oc] = sum_px q_h*k_h ----------------
// q_h = Wq @ x_h, k_h = Wk @ y_h at each pixel; never stored.
__global__ __launch_bounds__(256, 2) void dsattn_pooledqk(
        const float* __restrict__ xh, const float* __restrict__ yh,
        const float* __restrict__ wq, const float* __restrict__ wk,
        float* __restrict__ pooled) {
    __shared__ float psum[64];
    const int tid = threadIdx.x;
    if (tid < 64) psum[tid] = 0.f;
    __syncthreads();
    const int g = blockIdx.x * 256 + tid;
    const int b = g >> 16;
    const int px = g & (NPX - 1);
    const size_t base = (size_t)b * IMGST + px;
    float xv[64], yv[64];
#pragma unroll
    for (int c = 0; c < 64; ++c) {
        xv[c] = xh[base + (size_t)c * NPX];
        yv[c] = yh[base + (size_t)c * NPX];
    }
    for (int oc = 0; oc < 64; ++oc) {
        float q = 0.f, k = 0.f;
#pragma unroll
        for (int c = 0; c < 64; ++c) {
            q = fmaf(wq[oc * 64 + c], xv[c], q);
            k = fmaf(wk[oc * 64 + c], yv[c], k);
        }
        float p = wave_sum(q * k);
        if ((tid & 63) == 0) atomicAdd(&psum[oc], p);
    }
    __syncthreads();
    if (tid < 64) atomicAdd(&pooled[b * 64 + tid], psum[tid]);
}

// ---------------- K3: high_att = tanh(W2 @ relu(W1 @ mean)) ----------------
__global__ void dsattn_highatt(const float* __restrict__ pooled,
                               const float* __restrict__ w1,
                               const float* __restrict__ w2,
                               float* __restrict__ hatt) {
    __shared__ float z[64];                 // 4 images x 16
    const int t = threadIdx.x;              // 256
    if (t < 64) {
        const int b = t >> 4, i = t & 15;
        float a = 0.f;
#pragma unroll
        for (int c = 0; c < 64; ++c) a = fmaf(w1[i * 64 + c], pooled[b * 64 + c], a);
        a *= (1.f / 65536.f);
        z[t] = fmaxf(a, 0.f);
    }
    __syncthreads();
    {
        const int b = t >> 6, oc = t & 63;
        float a = 0.f;
#pragma unroll
        for (int i = 0; i < 16; ++i) a = fmaf(w2[oc * 16 + i], z[b * 16 + i], a);
        hatt[t] = tanhf(a);
    }
}

// ---------------- K4: low-path Gram + row sumsq (q_l/k_l never stored) ----------------
__global__ __launch_bounds__(256, 2) void dsattn_lowgram(
        const float* __restrict__ x, const float* __restrict__ y,
        const float* __restrict__ wql, const float* __restrict__ wkl,
        float* __restrict__ Gg, float* __restrict__ qssg, float* __restrict__ kssg) {
    __shared__ float Gl[512];
    __shared__ float qls[64], kls[64];
    const int tid = threadIdx.x;
    for (int i = tid; i < 512; i += 256) Gl[i] = 0.f;
    if (tid < 64) { qls[tid] = 0.f; kls[tid] = 0.f; }
    __syncthreads();
    const int g = blockIdx.x * 256 + tid;
    const int b = g >> 14;                 // 16384 pooled px per image
    const int pp = g & (NPP - 1);
    const int i = pp >> 7, j = pp & 127;
    const size_t base = (size_t)b * IMGST + (size_t)(2 * i) * 256 + 2 * j;
    float xp[64], yp[64];
#pragma unroll
    for (int c = 0; c < 64; ++c) {
        const size_t o = base + (size_t)c * NPX;
        xp[c] = 0.25f * (x[o] + x[o + 1] + x[o + 256] + x[o + 257]);
        yp[c] = 0.25f * (y[o] + y[o + 1] + y[o + 256] + y[o + 257]);
    }
    for (int h = 0; h < 8; ++h) {
        float q[8], k[8];
#pragma unroll
        for (int r = 0; r < 8; ++r) {
            float a = 0.f, bb = 0.f;
#pragma unroll
            for (int c = 0; c < 64; ++c) {
                a  = fmaf(wql[(h * 8 + r) * 64 + c], xp[c], a);
                bb = fmaf(wkl[(h * 8 + r) * 64 + c], yp[c], bb);
            }
            q[r] = a; k[r] = bb;
        }
#pragma unroll
        for (int r = 0; r < 8; ++r) {
            float vq = wave_sum(q[r] * q[r]);
            float vk = wave_sum(k[r] * k[r]);
            if ((tid & 63) == 0) {
                atomicAdd(&qls[h * 8 + r], vq);
                atomicAdd(&kls[h * 8 + r], vk);
            }
        }
#pragma unroll
        for (int r = 0; r < 8; ++r)
#pragma unroll
            for (int d = 0; d < 8; ++d) {
                float v = wave_sum(q[r] * k[d]);
                if ((tid & 63) == 0) atomicAdd(&Gl[h * 64 + r * 8 + d], v);
            }
    }
    __syncthreads();
    for (int i2 = tid; i2 < 512; i2 += 256) atomicAdd(&Gg[b * 512 + i2], Gl[i2]);
    if (tid < 64) {
        atomicAdd(&qssg[b * 64 + tid], qls[tid]);
        atomicAdd(&kssg[b * 64 + tid], kls[tid]);
    }
}

// ---------------- K5: normalize Gram, softmax -> att ----------------
__global__ void dsattn_attfin(const float* __restrict__ Gg,
                              const float* __restrict__ qss, const float* __restrict__ kss,
                              const float* __restrict__ temp, float* __restrict__ att) {
    const int t = threadIdx.x;             // 256 = 4b * 8h * 8c
    const int b = t >> 6, r = t & 63;
    const int h = r >> 3, ci = r & 7;
    float nq = fmaxf(sqrtf(qss[b * 64 + r]), 1e-12f);
    float a[8];
    float m = -1e30f;
#pragma unroll
    for (int d = 0; d < 8; ++d) {
        float nk = fmaxf(sqrtf(kss[b * 64 + h * 8 + d]), 1e-12f);
        a[d] = Gg[b * 512 + h * 64 + ci * 8 + d] / (nq * nk) * temp[h];
        m = fmaxf(m, a[d]);
    }
    float s = 0.f;
#pragma unroll
    for (int d = 0; d < 8; ++d) { a[d] = expf(a[d] - m); s += a[d]; }
    const float inv = 1.f / s;
#pragma unroll
    for (int d = 0; d < 8; ++d) att[b * 512 + h * 64 + ci * 8 + d] = a[d] * inv;
}

// ---------------- K6: v_l, v_h (recomputed), gate, low mix, proj ----------------
__global__ __launch_bounds__(256, 2) void dsattn_final(
        const float* __restrict__ y, const float* __restrict__ xh,
        const float* __restrict__ wvh, const float* __restrict__ wvl,
        const float* __restrict__ wproj, const float* __restrict__ att,
        const float* __restrict__ hatt, float* __restrict__ out) {
    const int tid = threadIdx.x;
    const int g = blockIdx.x * 256 + tid;
    const int b = g >> 16;
    const int px = g & (NPX - 1);
    const size_t base = (size_t)b * IMGST + px;

    float yv[64];
#pragma unroll
    for (int c = 0; c < 64; ++c) yv[c] = y[base + (size_t)c * NPX];
    float vl[64];
#pragma unroll
    for (int oc = 0; oc < 64; ++oc) {
        float a = 0.f;
#pragma unroll
        for (int c = 0; c < 64; ++c) a = fmaf(wvl[oc * 64 + c], yv[c], a);
        vl[oc] = a;
    }
    float xv[64];
#pragma unroll
    for (int c = 0; c < 64; ++c) xv[c] = xh[base + (size_t)c * NPX];

    float acc[64];
#pragma unroll
    for (int o = 0; o < 64; ++o) acc[o] = 0.f;

#pragma unroll
    for (int h = 0; h < 8; ++h) {
        for (int ci = 0; ci < 8; ++ci) {            // runtime loop (uniform)
            const int c = h * 8 + ci;
            float vh = 0.f;
#pragma unroll
            for (int cc = 0; cc < 64; ++cc) vh = fmaf(wvh[c * 64 + cc], xv[cc], vh);
            float u = hatt[b * 64 + c] * vh;
#pragma unroll
            for (int d = 0; d < 8; ++d)
                u = fmaf(att[b * 512 + h * 64 + ci * 8 + d], vl[h * 8 + d], u);
#pragma unroll
            for (int o = 0; o < 64; ++o) acc[o] = fmaf(wproj[o * 64 + c], u, acc[o]);
        }
    }
#pragma unroll
    for (int o = 0; o < 64; ++o) out[base + (size_t)o * NPX] = acc[o];
}

// ---------------- launch ----------------
extern "C" void kernel_launch(void* const* d_in, const int* in_sizes, int n_in,
                              void* d_out, int out_size, void* d_ws, size_t ws_size,
                              hipStream_t stream) {
    const float* x      = (const float*)d_in[0];
    const float* y      = (const float*)d_in[1];
    const float* hp1_w3 = (const float*)d_in[2];
    const float* hp1_w5 = (const float*)d_in[3];
    const float* hp1_w7 = (const float*)d_in[4];
    const float* hp2_w3 = (const float*)d_in[5];
    const float* hp2_w5 = (const float*)d_in[6];
    const float* hp2_w7 = (const float*)d_in[7];
    const float* qh_w   = (const float*)d_in[8];
    const float* kh_w   = (const float*)d_in[9];
    const float* vh_w   = (const float*)d_in[10];
    const float* ql_w   = (const float*)d_in[11];
    const float* kl_w   = (const float*)d_in[12];
    const float* vl_w   = (const float*)d_in[13];
    const float* proj_w = (const float*)d_in[14];
    const float* attn_w1 = (const float*)d_in[15];
    const float* attn_w2 = (const float*)d_in[16];
    const float* temperature = (const float*)d_in[17];

    float* out = (float*)d_out;
    float* xh  = (float*)d_ws;              // 16777216 floats
    float* yh  = out;                        // reuse d_out as y_h scratch (dead until K6)
    float* small  = xh + (size_t)NB * IMGST; // small scratch region
    float* pooled = small;                   // 256
    float* Gg     = small + 256;             // 2048
    float* qss    = small + 2304;            // 256
    float* kss    = small + 2560;            // 256
    float* att    = small + 2816;            // 2048
    float* hatt   = small + 4864;            // 256  (total 5120 floats)

    hipMemsetAsync(small, 0, 5120 * sizeof(float), stream);

    dsattn_dwconv<<<dim3(64, 256), 256, 0, stream>>>(x, xh, hp1_w3, hp1_w5, hp1_w7);
    dsattn_dwconv<<<dim3(64, 256), 256, 0, stream>>>(y, yh, hp2_w3, hp2_w5, hp2_w7);
    dsattn_pooledqk<<<1024, 256, 0, stream>>>(xh, yh, qh_w, kh_w, pooled);
    dsattn_highatt<<<1, 256, 0, stream>>>(pooled, attn_w1, attn_w2, hatt);
    dsattn_lowgram<<<256, 256, 0, stream>>>(x, y, ql_w, kl_w, Gg, qss, kss);
    dsattn_attfin<<<1, 256, 0, stream>>>(Gg, qss, kss, temperature, att);
    dsattn_final<<<1024, 256, 0, stream>>>(y, xh, vh_w, vl_w, proj_w, att, hatt, out);
}

// Round 2
// 681.441 us; speedup vs baseline: 1.9983x; 1.9983x over previous
//
#include <hip/hip_runtime.h>
#include <hip/hip_bf16.h>
#include <math.h>

#define NPX   65536          // 256*256
#define IMGST 4194304        // 64*65536
#define NB    4

// ================= K1: depthwise conv (unchanged, worked) =================
__global__ __launch_bounds__(256) void dsattn_dwconv(
        const float* __restrict__ in, float* __restrict__ outp,
        const float* __restrict__ w3, const float* __restrict__ w5,
        const float* __restrict__ w7) {
    __shared__ float sm[38 * 38];
    __shared__ float wsm[49];
    const int tid = threadIdx.x;
    const int tile = blockIdx.x;
    const int tx = tile & 7, ty = tile >> 3;
    const int bc = blockIdx.y;            // b*64 + c
    const int c = bc & 63;
    const float* plane = in + (size_t)bc * NPX;
    const int row0 = ty * 32 - 3, col0 = tx * 32 - 3;

    for (int idx = tid; idx < 38 * 38; idx += 256) {
        int r = idx / 38, cc = idx - r * 38;
        int gr = row0 + r, gc = col0 + cc;
        float v = 0.f;
        if ((unsigned)gr < 256u && (unsigned)gc < 256u) v = plane[gr * 256 + gc];
        sm[idx] = v;
    }
    int k; const float* wp;
    if (c < 32)      { k = 3; wp = w3 + c * 9; }
    else if (c < 48) { k = 5; wp = w5 + (c - 32) * 25; }
    else             { k = 7; wp = w7 + (c - 48) * 49; }
    if (tid < k * k) wsm[tid] = wp[tid];
    __syncthreads();

    const int lx = tid & 31, ly0 = tid >> 5;
    float* oplane = outp + (size_t)bc * NPX;
#pragma unroll
    for (int rr = 0; rr < 4; ++rr) {
        const int ly = ly0 + rr * 8;
        float acc = 0.f;
        if (k == 3) {
#pragma unroll
            for (int dy = 0; dy < 3; ++dy)
#pragma unroll
                for (int dx = 0; dx < 3; ++dx)
                    acc = fmaf(wsm[dy * 3 + dx], sm[(ly + 2 + dy) * 38 + lx + 2 + dx], acc);
        } else if (k == 5) {
#pragma unroll
            for (int dy = 0; dy < 5; ++dy)
#pragma unroll
                for (int dx = 0; dx < 5; ++dx)
                    acc = fmaf(wsm[dy * 5 + dx], sm[(ly + 1 + dy) * 38 + lx + 1 + dx], acc);
        } else {
#pragma unroll
            for (int dy = 0; dy < 7; ++dy)
#pragma unroll
                for (int dx = 0; dx < 7; ++dx)
                    acc = fmaf(wsm[dy * 7 + dx], sm[(ly + dy) * 38 + lx + dx], acc);
        }
        oplane[(ty * 32 + ly) * 256 + tx * 32 + lx] = acc;
    }
}

// ================= K2: cross-Gram S_b = xh @ yh^T, K-split partials =================
// grid (128 chunks, 4 img), 256 thr. Thread: 4x4 tile of 64x64 S. LDS stride 65.
__global__ __launch_bounds__(256) void dsattn_crossgram(
        const float* __restrict__ xh, const float* __restrict__ yh,
        float* __restrict__ Spart) {
    __shared__ float sx[64 * 65];
    __shared__ float sy[64 * 65];
    const int tid = threadIdx.x;
    const int chunk = blockIdx.x;
    const int b = blockIdx.y;
    const int rt = tid >> 4;      // 0..15
    const int ct = tid & 15;      // 0..15
    float acc[16];
#pragma unroll
    for (int i = 0; i < 16; ++i) acc[i] = 0.f;
    const size_t ibase = (size_t)b * IMGST + chunk * 512;

    for (int tile = 0; tile < 8; ++tile) {
        __syncthreads();
        for (int idx = tid; idx < 4096; idx += 256) {
            const int c = idx >> 6, p = idx & 63;
            const size_t g = ibase + (size_t)c * NPX + tile * 64 + p;
            sx[p * 65 + c] = xh[g];
            sy[p * 65 + c] = yh[g];
        }
        __syncthreads();
        for (int p = 0; p < 64; ++p) {
            float xr[4], yc[4];
#pragma unroll
            for (int j = 0; j < 4; ++j) {
                xr[j] = sx[p * 65 + rt * 4 + j];
                yc[j] = sy[p * 65 + ct * 4 + j];
            }
#pragma unroll
            for (int r = 0; r < 4; ++r)
#pragma unroll
                for (int c2 = 0; c2 < 4; ++c2)
                    acc[r * 4 + c2] = fmaf(xr[r], yc[c2], acc[r * 4 + c2]);
        }
    }
    float* outp = Spart + ((size_t)b * 128 + chunk) * 4096;
#pragma unroll
    for (int r = 0; r < 4; ++r)
#pragma unroll
        for (int c2 = 0; c2 < 4; ++c2)
            outp[(rt * 4 + r) * 64 + ct * 4 + c2] = acc[r * 4 + c2];
}

// ================= K2b: reduce S partials -> Sred[4][4096] =================
__global__ __launch_bounds__(256) void dsattn_reduceS(
        const float* __restrict__ Spart, float* __restrict__ Sred) {
    const int i = blockIdx.x * 256 + threadIdx.x;   // 0..4095
    const int b = blockIdx.y;
    const float* p = Spart + (size_t)b * 128 * 4096 + i;
    float s = 0.f;
#pragma unroll 4
    for (int k = 0; k < 128; ++k) s += p[(size_t)k * 4096];
    Sred[b * 4096 + i] = s;
}

// ================= K3: pooled = diag(Wq S Wk^T)/NPX -> MLP -> hatt =================
__global__ __launch_bounds__(256) void dsattn_highatt(
        const float* __restrict__ Sred, const float* __restrict__ wq,
        const float* __restrict__ wk, const float* __restrict__ w1,
        const float* __restrict__ w2, float* __restrict__ hatt) {
    __shared__ float S[4096];
    __shared__ float t1[4096];
    __shared__ float pooled[64];
    __shared__ float z[16];
    const int b = blockIdx.x, tid = threadIdx.x;
    for (int i = tid; i < 4096; i += 256) S[i] = Sred[b * 4096 + i];
    __syncthreads();
    for (int i = tid; i < 4096; i += 256) {
        const int oc = i >> 6, cp = i & 63;
        float s = 0.f;
#pragma unroll
        for (int c = 0; c < 64; ++c) s = fmaf(wq[oc * 64 + c], S[c * 64 + cp], s);
        t1[i] = s;
    }
    __syncthreads();
    if (tid < 64) {
        float s = 0.f;
#pragma unroll
        for (int cp = 0; cp < 64; ++cp) s = fmaf(wk[tid * 64 + cp], t1[tid * 64 + cp], s);
        pooled[tid] = s * (1.f / 65536.f);
    }
    __syncthreads();
    if (tid < 16) {
        float a = 0.f;
#pragma unroll
        for (int c = 0; c < 64; ++c) a = fmaf(w1[tid * 64 + c], pooled[c], a);
        z[tid] = fmaxf(a, 0.f);
    }
    __syncthreads();
    if (tid < 64) {
        float a = 0.f;
#pragma unroll
        for (int i = 0; i < 16; ++i) a = fmaf(w2[tid * 16 + i], z[i], a);
        hatt[b * 64 + tid] = tanhf(a);
    }
}

// ================= K4: pooled Grams (Sxy, Sxx, Syy), K-split partials =================
// grid (128 pooled rows, 4 img). chunk = pooled row i (128 pooled px).
__global__ __launch_bounds__(256) void dsattn_poolgram(
        const float* __restrict__ x, const float* __restrict__ y,
        float* __restrict__ Ppart) {
    __shared__ float sx[64 * 65];
    __shared__ float sy[64 * 65];
    const int tid = threadIdx.x;
    const int irow = blockIdx.x;   // pooled row
    const int b = blockIdx.y;
    const int rt = tid >> 4, ct = tid & 15;
    float aXY[16], aXX[16], aYY[16];
#pragma unroll
    for (int i = 0; i < 16; ++i) { aXY[i] = 0.f; aXX[i] = 0.f; aYY[i] = 0.f; }
    const size_t ibase = (size_t)b * IMGST + (size_t)(2 * irow) * 256;

    for (int tile = 0; tile < 2; ++tile) {
        __syncthreads();
        for (int idx = tid; idx < 4096; idx += 256) {
            const int c = idx >> 6, jj = idx & 63;
            const size_t g = ibase + (size_t)c * NPX + 2 * (tile * 64 + jj);
            const float* px0 = x + g;
            const float* py0 = y + g;
            sx[jj * 65 + c] = 0.25f * (px0[0] + px0[1] + px0[256] + px0[257]);
            sy[jj * 65 + c] = 0.25f * (py0[0] + py0[1] + py0[256] + py0[257]);
        }
        __syncthreads();
        for (int p = 0; p < 64; ++p) {
            float xr[4], xc[4], yr[4], yc[4];
#pragma unroll
            for (int j = 0; j < 4; ++j) {
                xr[j] = sx[p * 65 + rt * 4 + j];
                xc[j] = sx[p * 65 + ct * 4 + j];
                yr[j] = sy[p * 65 + rt * 4 + j];
                yc[j] = sy[p * 65 + ct * 4 + j];
            }
#pragma unroll
            for (int r = 0; r < 4; ++r)
#pragma unroll
                for (int c2 = 0; c2 < 4; ++c2) {
                    aXY[r * 4 + c2] = fmaf(xr[r], yc[c2], aXY[r * 4 + c2]);
                    aXX[r * 4 + c2] = fmaf(xr[r], xc[c2], aXX[r * 4 + c2]);
                    aYY[r * 4 + c2] = fmaf(yr[r], yc[c2], aYY[r * 4 + c2]);
                }
        }
    }
    float* outp = Ppart + ((size_t)b * 128 + irow) * 12288;
#pragma unroll
    for (int r = 0; r < 4; ++r)
#pragma unroll
        for (int c2 = 0; c2 < 4; ++c2) {
            const int o = (rt * 4 + r) * 64 + ct * 4 + c2;
            outp[o]        = aXY[r * 4 + c2];
            outp[4096 + o] = aXX[r * 4 + c2];
            outp[8192 + o] = aYY[r * 4 + c2];
        }
}

// ================= K4b: reduce P partials -> Pred[4][12288] =================
__global__ __launch_bounds__(256) void dsattn_reduceP(
        const float* __restrict__ Ppart, float* __restrict__ Pred) {
    const int i = blockIdx.x * 256 + threadIdx.x;   // 0..12287
    const int b = blockIdx.y;
    const float* p = Ppart + (size_t)b * 128 * 12288 + i;
    float s = 0.f;
#pragma unroll 4
    for (int k = 0; k < 128; ++k) s += p[(size_t)k * 12288];
    Pred[b * 12288 + i] = s;
}

// ================= K5: norms, softmax, fold -> At, Bt =================
__global__ __launch_bounds__(256) void dsattn_attfold(
        const float* __restrict__ Pred, const float* __restrict__ wql,
        const float* __restrict__ wkl, const float* __restrict__ wvl,
        const float* __restrict__ wvh, const float* __restrict__ wproj,
        const float* __restrict__ temp, const float* __restrict__ hatt,
        float* __restrict__ At, float* __restrict__ Bt) {
    __shared__ float S[4096];
    __shared__ float P1[4096];
    __shared__ float nq2[64], nk2[64];
    __shared__ float att[512];
    __shared__ float red[256];
    __shared__ float hm[64];
    __shared__ float G[512];
    const int b = blockIdx.x, tid = threadIdx.x;
    if (tid < 64) hm[tid] = hatt[b * 64 + tid];
    const float* Pb = Pred + (size_t)b * 12288;

    // ---- Sxx -> nq2 ----
    for (int i = tid; i < 4096; i += 256) S[i] = Pb[4096 + i];
    __syncthreads();
    {
        const int r = tid >> 2, part = tid & 3;
        float s = 0.f;
        for (int cp = part * 16; cp < part * 16 + 16; ++cp) {
            float inner = 0.f;
#pragma unroll
            for (int cc = 0; cc < 64; ++cc) inner = fmaf(wql[r * 64 + cc], S[cc * 64 + cp], inner);
            s = fmaf(inner, wql[r * 64 + cp], s);
        }
        red[tid] = s;
    }
    __syncthreads();
    if (tid < 64) nq2[tid] = red[tid * 4] + red[tid * 4 + 1] + red[tid * 4 + 2] + red[tid * 4 + 3];
    __syncthreads();

    // ---- Syy -> nk2 ----
    for (int i = tid; i < 4096; i += 256) S[i] = Pb[8192 + i];
    __syncthreads();
    {
        const int r = tid >> 2, part = tid & 3;
        float s = 0.f;
        for (int cp = part * 16; cp < part * 16 + 16; ++cp) {
            float inner = 0.f;
#pragma unroll
            for (int cc = 0; cc < 64; ++cc) inner = fmaf(wkl[r * 64 + cc], S[cc * 64 + cp], inner);
            s = fmaf(inner, wkl[r * 64 + cp], s);
        }
        red[tid] = s;
    }
    __syncthreads();
    if (tid < 64) nk2[tid] = red[tid * 4] + red[tid * 4 + 1] + red[tid * 4 + 2] + red[tid * 4 + 3];
    __syncthreads();

    // ---- Sxy -> P1 = Wql @ Sxy ----
    for (int i = tid; i < 4096; i += 256) S[i] = Pb[i];
    __syncthreads();
    for (int i = tid; i < 4096; i += 256) {
        const int r = i >> 6, cp = i & 63;
        float s = 0.f;
#pragma unroll
        for (int c = 0; c < 64; ++c) s = fmaf(wql[r * 64 + c], S[c * 64 + cp], s);
        P1[i] = s;
    }
    __syncthreads();
    // ---- G[h][r][d] = P1[h*8+r,:] . wkl[h*8+d,:] ----
    for (int i = tid; i < 512; i += 256) {
        const int h = i >> 6, r = (i >> 3) & 7, d = i & 7;
        const int qrow = h * 8 + r, krow = h * 8 + d;
        float s = 0.f;
#pragma unroll
        for (int c = 0; c < 64; ++c) s = fmaf(P1[qrow * 64 + c], wkl[krow * 64 + c], s);
        G[i] = s;
    }
    __syncthreads();
    // ---- softmax rows ----
    if (tid < 64) {
        const int h = tid >> 3;
        const float tpr = temp[h];
        const float nq = fmaxf(sqrtf(nq2[tid]), 1e-12f);
        float a[8], m = -1e30f;
#pragma unroll
        for (int d = 0; d < 8; ++d) {
            const float nk = fmaxf(sqrtf(nk2[h * 8 + d]), 1e-12f);
            a[d] = G[tid * 8 + d] / (nq * nk) * tpr;
            m = fmaxf(m, a[d]);
        }
        float ssum = 0.f;
#pragma unroll
        for (int d = 0; d < 8; ++d) { a[d] = expf(a[d] - m); ssum += a[d]; }
        const float inv = 1.f / ssum;
#pragma unroll
        for (int d = 0; d < 8; ++d) att[tid * 8 + d] = a[d] * inv;
    }
    __syncthreads();
    // ---- tvl[m][c] = sum_d att[m,d] * wvl[h*8+d, c]  (reuse S) ----
    for (int i = tid; i < 4096; i += 256) {
        const int m = i >> 6, c = i & 63;
        const int h = m >> 3;
        float s = 0.f;
#pragma unroll
        for (int d = 0; d < 8; ++d) s = fmaf(att[m * 8 + d], wvl[(h * 8 + d) * 64 + c], s);
        S[i] = s;
    }
    __syncthreads();
    // ---- At[c][o], Bt[c][o] ----
    for (int i = tid; i < 4096; i += 256) {
        const int c = i >> 6, o = i & 63;
        float sa = 0.f, sb = 0.f;
#pragma unroll
        for (int m = 0; m < 64; ++m) {
            const float wp = wproj[o * 64 + m];
            sa = fmaf(wp * hm[m], wvh[m * 64 + c], sa);
            sb = fmaf(wp, S[m * 64 + c], sb);
        }
        At[b * 4096 + i] = sa;
        Bt[b * 4096 + i] = sb;
    }
}

// ================= K6: out = A_b @ xh + B_b @ y =================
__global__ __launch_bounds__(256) void dsattn_final(
        const float* __restrict__ xh, const float* __restrict__ y,
        const float* __restrict__ At, const float* __restrict__ Bt,
        float* __restrict__ out) {
    const int g = blockIdx.x * 256 + threadIdx.x;
    const int b = g >> 16;
    const int px = g & (NPX - 1);
    const float* Ab = At + b * 4096;
    const float* Bb = Bt + b * 4096;
    const size_t base = (size_t)b * IMGST + px;

    float acc[64];
#pragma unroll
    for (int o = 0; o < 64; ++o) acc[o] = 0.f;

    for (int c = 0; c < 64; ++c) {
        const float xv = xh[base + (size_t)c * NPX];
        const float yv = y[base + (size_t)c * NPX];
#pragma unroll
        for (int o = 0; o < 64; ++o) acc[o] = fmaf(Ab[c * 64 + o], xv, acc[o]);
#pragma unroll
        for (int o = 0; o < 64; ++o) acc[o] = fmaf(Bb[c * 64 + o], yv, acc[o]);
    }
#pragma unroll
    for (int o = 0; o < 64; ++o) out[base + (size_t)o * NPX] = acc[o];
}

// ================= launch =================
extern "C" void kernel_launch(void* const* d_in, const int* in_sizes, int n_in,
                              void* d_out, int out_size, void* d_ws, size_t ws_size,
                              hipStream_t stream) {
    const float* x      = (const float*)d_in[0];
    const float* y      = (const float*)d_in[1];
    const float* hp1_w3 = (const float*)d_in[2];
    const float* hp1_w5 = (const float*)d_in[3];
    const float* hp1_w7 = (const float*)d_in[4];
    const float* hp2_w3 = (const float*)d_in[5];
    const float* hp2_w5 = (const float*)d_in[6];
    const float* hp2_w7 = (const float*)d_in[7];
    const float* qh_w   = (const float*)d_in[8];
    const float* kh_w   = (const float*)d_in[9];
    const float* vh_w   = (const float*)d_in[10];
    const float* ql_w   = (const float*)d_in[11];
    const float* kl_w   = (const float*)d_in[12];
    const float* vl_w   = (const float*)d_in[13];
    const float* proj_w = (const float*)d_in[14];
    const float* attn_w1 = (const float*)d_in[15];
    const float* attn_w2 = (const float*)d_in[16];
    const float* temperature = (const float*)d_in[17];

    float* out = (float*)d_out;

    // ws layout (floats):
    float* xh    = (float*)d_ws;                     // 16,777,216
    float* Spart = xh + (size_t)NB * IMGST;          // +2,097,152 -> 18,874,368
    float* small = Spart + (size_t)4 * 128 * 4096;
    float* Sred  = small;                            // 16,384
    float* Pred  = Sred + 16384;                     // 49,152
    float* hatt  = Pred + 49152;                     // 256
    float* At    = hatt + 256;                       // 16,384
    float* Bt    = At + 16384;                       // 16,384  (total ~75.9 MB)

    float* yh    = out;                              // d_out scratch until crossgram done
    float* Ppart = out;                              // d_out scratch after crossgram (6.3M floats)

    dsattn_dwconv<<<dim3(64, 256), 256, 0, stream>>>(x, xh, hp1_w3, hp1_w5, hp1_w7);
    dsattn_dwconv<<<dim3(64, 256), 256, 0, stream>>>(y, yh, hp2_w3, hp2_w5, hp2_w7);
    dsattn_crossgram<<<dim3(128, 4), 256, 0, stream>>>(xh, yh, Spart);
    dsattn_reduceS<<<dim3(16, 4), 256, 0, stream>>>(Spart, Sred);
    dsattn_highatt<<<4, 256, 0, stream>>>(Sred, qh_w, kh_w, attn_w1, attn_w2, hatt);
    dsattn_poolgram<<<dim3(128, 4), 256, 0, stream>>>(x, y, Ppart);   // overwrites yh (dead)
    dsattn_reduceP<<<dim3(48, 4), 256, 0, stream>>>(Ppart, Pred);
    dsattn_attfold<<<4, 256, 0, stream>>>(Pred, ql_w, kl_w, vl_w, vh_w, proj_w,
                                          temperature, hatt, At, Bt);
    dsattn_final<<<1024, 256, 0, stream>>>(xh, y, At, Bt, out);       // overwrites Ppart
}

// Round 4
// 435.397 us; speedup vs baseline: 3.1276x; 1.5651x over previous
//
#include <hip/hip_runtime.h>
#include <hip/hip_bf16.h>
#include <math.h>

#define NPX   65536          // 256*256
#define IMGST 4194304        // 64*65536
#define NB    4

// ================= K1: depthwise conv (unchanged, worked) =================
__global__ __launch_bounds__(256) void dsattn_dwconv(
        const float* __restrict__ in, float* __restrict__ outp,
        const float* __restrict__ w3, const float* __restrict__ w5,
        const float* __restrict__ w7) {
    __shared__ float sm[38 * 38];
    __shared__ float wsm[49];
    const int tid = threadIdx.x;
    const int tile = blockIdx.x;
    const int tx = tile & 7, ty = tile >> 3;
    const int bc = blockIdx.y;            // b*64 + c
    const int c = bc & 63;
    const float* plane = in + (size_t)bc * NPX;
    const int row0 = ty * 32 - 3, col0 = tx * 32 - 3;

    for (int idx = tid; idx < 38 * 38; idx += 256) {
        int r = idx / 38, cc = idx - r * 38;
        int gr = row0 + r, gc = col0 + cc;
        float v = 0.f;
        if ((unsigned)gr < 256u && (unsigned)gc < 256u) v = plane[gr * 256 + gc];
        sm[idx] = v;
    }
    int k; const float* wp;
    if (c < 32)      { k = 3; wp = w3 + c * 9; }
    else if (c < 48) { k = 5; wp = w5 + (c - 32) * 25; }
    else             { k = 7; wp = w7 + (c - 48) * 49; }
    if (tid < k * k) wsm[tid] = wp[tid];
    __syncthreads();

    const int lx = tid & 31, ly0 = tid >> 5;
    float* oplane = outp + (size_t)bc * NPX;
#pragma unroll
    for (int rr = 0; rr < 4; ++rr) {
        const int ly = ly0 + rr * 8;
        float acc = 0.f;
        if (k == 3) {
#pragma unroll
            for (int dy = 0; dy < 3; ++dy)
#pragma unroll
                for (int dx = 0; dx < 3; ++dx)
                    acc = fmaf(wsm[dy * 3 + dx], sm[(ly + 2 + dy) * 38 + lx + 2 + dx], acc);
        } else if (k == 5) {
#pragma unroll
            for (int dy = 0; dy < 5; ++dy)
#pragma unroll
                for (int dx = 0; dx < 5; ++dx)
                    acc = fmaf(wsm[dy * 5 + dx], sm[(ly + 1 + dy) * 38 + lx + 1 + dx], acc);
        } else {
#pragma unroll
            for (int dy = 0; dy < 7; ++dy)
#pragma unroll
                for (int dx = 0; dx < 7; ++dx)
                    acc = fmaf(wsm[dy * 7 + dx], sm[(ly + dy) * 38 + lx + dx], acc);
        }
        oplane[(ty * 32 + ly) * 256 + tx * 32 + lx] = acc;
    }
}

// ================= K2: cross-Gram S_b = xh @ yh^T, K-split partials =================
__global__ __launch_bounds__(256) void dsattn_crossgram(
        const float* __restrict__ xh, const float* __restrict__ yh,
        float* __restrict__ Spart) {
    __shared__ float sx[64 * 65];
    __shared__ float sy[64 * 65];
    const int tid = threadIdx.x;
    const int chunk = blockIdx.x;
    const int b = blockIdx.y;
    const int rt = tid >> 4;      // 0..15
    const int ct = tid & 15;      // 0..15
    float acc[16];
#pragma unroll
    for (int i = 0; i < 16; ++i) acc[i] = 0.f;
    const size_t ibase = (size_t)b * IMGST + chunk * 512;

    for (int tile = 0; tile < 8; ++tile) {
        __syncthreads();
        for (int idx = tid; idx < 4096; idx += 256) {
            const int c = idx >> 6, p = idx & 63;
            const size_t g = ibase + (size_t)c * NPX + tile * 64 + p;
            sx[p * 65 + c] = xh[g];
            sy[p * 65 + c] = yh[g];
        }
        __syncthreads();
        for (int p = 0; p < 64; ++p) {
            float xr[4], yc[4];
#pragma unroll
            for (int j = 0; j < 4; ++j) {
                xr[j] = sx[p * 65 + rt * 4 + j];
                yc[j] = sy[p * 65 + ct * 4 + j];
            }
#pragma unroll
            for (int r = 0; r < 4; ++r)
#pragma unroll
                for (int c2 = 0; c2 < 4; ++c2)
                    acc[r * 4 + c2] = fmaf(xr[r], yc[c2], acc[r * 4 + c2]);
        }
    }
    float* outp = Spart + ((size_t)b * 128 + chunk) * 4096;
#pragma unroll
    for (int r = 0; r < 4; ++r)
#pragma unroll
        for (int c2 = 0; c2 < 4; ++c2)
            outp[(rt * 4 + r) * 64 + ct * 4 + c2] = acc[r * 4 + c2];
}

// ================= K2b: reduce S partials -> Sred[4][4096] =================
__global__ __launch_bounds__(256) void dsattn_reduceS(
        const float* __restrict__ Spart, float* __restrict__ Sred) {
    const int i = blockIdx.x * 256 + threadIdx.x;   // 0..4095
    const int b = blockIdx.y;
    const float* p = Spart + (size_t)b * 128 * 4096 + i;
    float s = 0.f;
#pragma unroll 4
    for (int k = 0; k < 128; ++k) s += p[(size_t)k * 4096];
    Sred[b * 4096 + i] = s;
}

// ================= K3: pooled = diag(Wq S Wk^T)/NPX -> MLP -> hatt =================
__global__ __launch_bounds__(256) void dsattn_highatt(
        const float* __restrict__ Sred, const float* __restrict__ wq,
        const float* __restrict__ wk, const float* __restrict__ w1,
        const float* __restrict__ w2, float* __restrict__ hatt) {
    __shared__ float S[4096];
    __shared__ float t1[4096];
    __shared__ float pooled[64];
    __shared__ float z[16];
    const int b = blockIdx.x, tid = threadIdx.x;
    for (int i = tid; i < 4096; i += 256) S[i] = Sred[b * 4096 + i];
    __syncthreads();
    for (int i = tid; i < 4096; i += 256) {
        const int oc = i >> 6, cp = i & 63;
        float s = 0.f;
#pragma unroll
        for (int c = 0; c < 64; ++c) s = fmaf(wq[oc * 64 + c], S[c * 64 + cp], s);
        t1[i] = s;
    }
    __syncthreads();
    if (tid < 64) {
        float s = 0.f;
#pragma unroll
        for (int cp = 0; cp < 64; ++cp) s = fmaf(wk[tid * 64 + cp], t1[tid * 64 + cp], s);
        pooled[tid] = s * (1.f / 65536.f);
    }
    __syncthreads();
    if (tid < 16) {
        float a = 0.f;
#pragma unroll
        for (int c = 0; c < 64; ++c) a = fmaf(w1[tid * 64 + c], pooled[c], a);
        z[tid] = fmaxf(a, 0.f);
    }
    __syncthreads();
    if (tid < 64) {
        float a = 0.f;
#pragma unroll
        for (int i = 0; i < 16; ++i) a = fmaf(w2[tid * 16 + i], z[i], a);
        hatt[b * 64 + tid] = tanhf(a);
    }
}

// ================= K4: pooled Grams (Sxy, Sxx, Syy), K-split partials =================
__global__ __launch_bounds__(256) void dsattn_poolgram(
        const float* __restrict__ x, const float* __restrict__ y,
        float* __restrict__ Ppart) {
    __shared__ float sx[64 * 65];
    __shared__ float sy[64 * 65];
    const int tid = threadIdx.x;
    const int irow = blockIdx.x;   // pooled row
    const int b = blockIdx.y;
    const int rt = tid >> 4, ct = tid & 15;
    float aXY[16], aXX[16], aYY[16];
#pragma unroll
    for (int i = 0; i < 16; ++i) { aXY[i] = 0.f; aXX[i] = 0.f; aYY[i] = 0.f; }
    const size_t ibase = (size_t)b * IMGST + (size_t)(2 * irow) * 256;

    for (int tile = 0; tile < 2; ++tile) {
        __syncthreads();
        for (int idx = tid; idx < 4096; idx += 256) {
            const int c = idx >> 6, jj = idx & 63;
            const size_t g = ibase + (size_t)c * NPX + 2 * (tile * 64 + jj);
            const float* px0 = x + g;
            const float* py0 = y + g;
            sx[jj * 65 + c] = 0.25f * (px0[0] + px0[1] + px0[256] + px0[257]);
            sy[jj * 65 + c] = 0.25f * (py0[0] + py0[1] + py0[256] + py0[257]);
        }
        __syncthreads();
        for (int p = 0; p < 64; ++p) {
            float xr[4], xc[4], yr[4], yc[4];
#pragma unroll
            for (int j = 0; j < 4; ++j) {
                xr[j] = sx[p * 65 + rt * 4 + j];
                xc[j] = sx[p * 65 + ct * 4 + j];
                yr[j] = sy[p * 65 + rt * 4 + j];
                yc[j] = sy[p * 65 + ct * 4 + j];
            }
#pragma unroll
            for (int r = 0; r < 4; ++r)
#pragma unroll
                for (int c2 = 0; c2 < 4; ++c2) {
                    aXY[r * 4 + c2] = fmaf(xr[r], yc[c2], aXY[r * 4 + c2]);
                    aXX[r * 4 + c2] = fmaf(xr[r], xc[c2], aXX[r * 4 + c2]);
                    aYY[r * 4 + c2] = fmaf(yr[r], yc[c2], aYY[r * 4 + c2]);
                }
        }
    }
    float* outp = Ppart + ((size_t)b * 128 + irow) * 12288;
#pragma unroll
    for (int r = 0; r < 4; ++r)
#pragma unroll
        for (int c2 = 0; c2 < 4; ++c2) {
            const int o = (rt * 4 + r) * 64 + ct * 4 + c2;
            outp[o]        = aXY[r * 4 + c2];
            outp[4096 + o] = aXX[r * 4 + c2];
            outp[8192 + o] = aYY[r * 4 + c2];
        }
}

// ================= K4b: reduce P partials -> Pred[4][12288] =================
__global__ __launch_bounds__(256) void dsattn_reduceP(
        const float* __restrict__ Ppart, float* __restrict__ Pred) {
    const int i = blockIdx.x * 256 + threadIdx.x;   // 0..12287
    const int b = blockIdx.y;
    const float* p = Ppart + (size_t)b * 128 * 12288 + i;
    float s = 0.f;
#pragma unroll 4
    for (int k = 0; k < 128; ++k) s += p[(size_t)k * 12288];
    Pred[b * 12288 + i] = s;
}

// ================= K5: norms, softmax, fold -> At, Bt =================
__global__ __launch_bounds__(256) void dsattn_attfold(
        const float* __restrict__ Pred, const float* __restrict__ wql,
        const float* __restrict__ wkl, const float* __restrict__ wvl,
        const float* __restrict__ wvh, const float* __restrict__ wproj,
        const float* __restrict__ temp, const float* __restrict__ hatt,
        float* __restrict__ At, float* __restrict__ Bt) {
    __shared__ float S[4096];
    __shared__ float P1[4096];
    __shared__ float nq2[64], nk2[64];
    __shared__ float att[512];
    __shared__ float red[256];
    __shared__ float hm[64];
    __shared__ float G[512];
    const int b = blockIdx.x, tid = threadIdx.x;
    if (tid < 64) hm[tid] = hatt[b * 64 + tid];
    const float* Pb = Pred + (size_t)b * 12288;

    // ---- Sxx -> nq2 ----
    for (int i = tid; i < 4096; i += 256) S[i] = Pb[4096 + i];
    __syncthreads();
    {
        const int r = tid >> 2, part = tid & 3;
        float s = 0.f;
        for (int cp = part * 16; cp < part * 16 + 16; ++cp) {
            float inner = 0.f;
#pragma unroll
            for (int cc = 0; cc < 64; ++cc) inner = fmaf(wql[r * 64 + cc], S[cc * 64 + cp], inner);
            s = fmaf(inner, wql[r * 64 + cp], s);
        }
        red[tid] = s;
    }
    __syncthreads();
    if (tid < 64) nq2[tid] = red[tid * 4] + red[tid * 4 + 1] + red[tid * 4 + 2] + red[tid * 4 + 3];
    __syncthreads();

    // ---- Syy -> nk2 ----
    for (int i = tid; i < 4096; i += 256) S[i] = Pb[8192 + i];
    __syncthreads();
    {
        const int r = tid >> 2, part = tid & 3;
        float s = 0.f;
        for (int cp = part * 16; cp < part * 16 + 16; ++cp) {
            float inner = 0.f;
#pragma unroll
            for (int cc = 0; cc < 64; ++cc) inner = fmaf(wkl[r * 64 + cc], S[cc * 64 + cp], inner);
            s = fmaf(inner, wkl[r * 64 + cp], s);
        }
        red[tid] = s;
    }
    __syncthreads();
    if (tid < 64) nk2[tid] = red[tid * 4] + red[tid * 4 + 1] + red[tid * 4 + 2] + red[tid * 4 + 3];
    __syncthreads();

    // ---- Sxy -> P1 = Wql @ Sxy ----
    for (int i = tid; i < 4096; i += 256) S[i] = Pb[i];
    __syncthreads();
    for (int i = tid; i < 4096; i += 256) {
        const int r = i >> 6, cp = i & 63;
        float s = 0.f;
#pragma unroll
        for (int c = 0; c < 64; ++c) s = fmaf(wql[r * 64 + c], S[c * 64 + cp], s);
        P1[i] = s;
    }
    __syncthreads();
    // ---- G[h][r][d] = P1[h*8+r,:] . wkl[h*8+d,:] ----
    for (int i = tid; i < 512; i += 256) {
        const int h = i >> 6, r = (i >> 3) & 7, d = i & 7;
        const int qrow = h * 8 + r, krow = h * 8 + d;
        float s = 0.f;
#pragma unroll
        for (int c = 0; c < 64; ++c) s = fmaf(P1[qrow * 64 + c], wkl[krow * 64 + c], s);
        G[i] = s;
    }
    __syncthreads();
    // ---- softmax rows ----
    if (tid < 64) {
        const int h = tid >> 3;
        const float tpr = temp[h];
        const float nq = fmaxf(sqrtf(nq2[tid]), 1e-12f);
        float a[8], m = -1e30f;
#pragma unroll
        for (int d = 0; d < 8; ++d) {
            const float nk = fmaxf(sqrtf(nk2[h * 8 + d]), 1e-12f);
            a[d] = G[tid * 8 + d] / (nq * nk) * tpr;
            m = fmaxf(m, a[d]);
        }
        float ssum = 0.f;
#pragma unroll
        for (int d = 0; d < 8; ++d) { a[d] = expf(a[d] - m); ssum += a[d]; }
        const float inv = 1.f / ssum;
#pragma unroll
        for (int d = 0; d < 8; ++d) att[tid * 8 + d] = a[d] * inv;
    }
    __syncthreads();
    // ---- tvl[m][c] = sum_d att[m,d] * wvl[h*8+d, c]  (reuse S) ----
    for (int i = tid; i < 4096; i += 256) {
        const int m = i >> 6, c = i & 63;
        const int h = m >> 3;
        float s = 0.f;
#pragma unroll
        for (int d = 0; d < 8; ++d) s = fmaf(att[m * 8 + d], wvl[(h * 8 + d) * 64 + c], s);
        S[i] = s;
    }
    __syncthreads();
    // ---- At[c][o], Bt[c][o] ----
    for (int i = tid; i < 4096; i += 256) {
        const int c = i >> 6, o = i & 63;
        float sa = 0.f, sb = 0.f;
#pragma unroll
        for (int m = 0; m < 64; ++m) {
            const float wp = wproj[o * 64 + m];
            sa = fmaf(wp * hm[m], wvh[m * 64 + c], sa);
            sb = fmaf(wp, S[m * 64 + c], sb);
        }
        At[b * 4096 + i] = sa;
        Bt[b * 4096 + i] = sb;
    }
}

// ================= K6: out = A_b @ xh + B_b @ y  (tiled, LDS, acc[16]) =================
// grid (1024 px-tiles, 4 img), 256 thr. Thread: 1 px (lane) x 16 oc (og=tid>>6).
__global__ __launch_bounds__(256) void dsattn_final(
        const float* __restrict__ xh, const float* __restrict__ y,
        const float* __restrict__ At, const float* __restrict__ Bt,
        float* __restrict__ out) {
    __shared__ float Al[4096];   // [c][o]
    __shared__ float Bl[4096];
    __shared__ float xs[4096];   // [c][p]
    __shared__ float ys[4096];
    const int tid = threadIdx.x;
    const int b = blockIdx.y;                 // wave-uniform image index
    const size_t base = (size_t)b * IMGST + (size_t)blockIdx.x * 64;

    for (int i = tid; i < 4096; i += 256) {
        Al[i] = At[b * 4096 + i];
        Bl[i] = Bt[b * 4096 + i];
        const int c = i >> 6, p = i & 63;
        const size_t g = base + (size_t)c * NPX + p;
        xs[i] = xh[g];
        ys[i] = y[g];
    }
    __syncthreads();

    const int p  = tid & 63;
    const int ob = (tid >> 6) * 16;
    float acc[16];
#pragma unroll
    for (int o = 0; o < 16; ++o) acc[o] = 0.f;

#pragma unroll 4
    for (int c = 0; c < 64; ++c) {
        const float xv = xs[c * 64 + p];
        const float yv = ys[c * 64 + p];
        const float4* Ar = reinterpret_cast<const float4*>(&Al[c * 64 + ob]);
        const float4* Br = reinterpret_cast<const float4*>(&Bl[c * 64 + ob]);
#pragma unroll
        for (int q = 0; q < 4; ++q) {
            const float4 a  = Ar[q];
            const float4 bb = Br[q];
            acc[q * 4 + 0] = fmaf(a.x, xv, acc[q * 4 + 0]);
            acc[q * 4 + 1] = fmaf(a.y, xv, acc[q * 4 + 1]);
            acc[q * 4 + 2] = fmaf(a.z, xv, acc[q * 4 + 2]);
            acc[q * 4 + 3] = fmaf(a.w, xv, acc[q * 4 + 3]);
            acc[q * 4 + 0] = fmaf(bb.x, yv, acc[q * 4 + 0]);
            acc[q * 4 + 1] = fmaf(bb.y, yv, acc[q * 4 + 1]);
            acc[q * 4 + 2] = fmaf(bb.z, yv, acc[q * 4 + 2]);
            acc[q * 4 + 3] = fmaf(bb.w, yv, acc[q * 4 + 3]);
        }
    }

    float* op = out + base;
#pragma unroll
    for (int o = 0; o < 16; ++o)
        op[(size_t)(ob + o) * NPX + p] = acc[o];
}

// ================= launch =================
extern "C" void kernel_launch(void* const* d_in, const int* in_sizes, int n_in,
                              void* d_out, int out_size, void* d_ws, size_t ws_size,
                              hipStream_t stream) {
    const float* x      = (const float*)d_in[0];
    const float* y      = (const float*)d_in[1];
    const float* hp1_w3 = (const float*)d_in[2];
    const float* hp1_w5 = (const float*)d_in[3];
    const float* hp1_w7 = (const float*)d_in[4];
    const float* hp2_w3 = (const float*)d_in[5];
    const float* hp2_w5 = (const float*)d_in[6];
    const float* hp2_w7 = (const float*)d_in[7];
    const float* qh_w   = (const float*)d_in[8];
    const float* kh_w   = (const float*)d_in[9];
    const float* vh_w   = (const float*)d_in[10];
    const float* ql_w   = (const float*)d_in[11];
    const float* kl_w   = (const float*)d_in[12];
    const float* vl_w   = (const float*)d_in[13];
    const float* proj_w = (const float*)d_in[14];
    const float* attn_w1 = (const float*)d_in[15];
    const float* attn_w2 = (const float*)d_in[16];
    const float* temperature = (const float*)d_in[17];

    float* out = (float*)d_out;

    // ws layout (floats):
    float* xh    = (float*)d_ws;                     // 16,777,216
    float* Spart = xh + (size_t)NB * IMGST;          // +2,097,152
    float* small = Spart + (size_t)4 * 128 * 4096;
    float* Sred  = small;                            // 16,384
    float* Pred  = Sred + 16384;                     // 49,152
    float* hatt  = Pred + 49152;                     // 256
    float* At    = hatt + 256;                       // 16,384
    float* Bt    = At + 16384;                       // 16,384

    float* yh    = out;                              // d_out scratch until crossgram done
    float* Ppart = out;                              // d_out scratch after crossgram

    dsattn_dwconv<<<dim3(64, 256), 256, 0, stream>>>(x, xh, hp1_w3, hp1_w5, hp1_w7);
    dsattn_dwconv<<<dim3(64, 256), 256, 0, stream>>>(y, yh, hp2_w3, hp2_w5, hp2_w7);
    dsattn_crossgram<<<dim3(128, 4), 256, 0, stream>>>(xh, yh, Spart);
    dsattn_reduceS<<<dim3(16, 4), 256, 0, stream>>>(Spart, Sred);
    dsattn_highatt<<<4, 256, 0, stream>>>(Sred, qh_w, kh_w, attn_w1, attn_w2, hatt);
    dsattn_poolgram<<<dim3(128, 4), 256, 0, stream>>>(x, y, Ppart);
    dsattn_reduceP<<<dim3(48, 4), 256, 0, stream>>>(Ppart, Pred);
    dsattn_attfold<<<4, 256, 0, stream>>>(Pred, ql_w, kl_w, vl_w, vh_w, proj_w,
                                          temperature, hatt, At, Bt);
    dsattn_final<<<dim3(1024, 4), 256, 0, stream>>>(xh, y, At, Bt, out);
}

// Round 5
// 329.070 us; speedup vs baseline: 4.1382x; 1.3231x over previous
//
#include <hip/hip_runtime.h>
#include <hip/hip_bf16.h>
#include <math.h>

#define NPX   65536          // 256*256
#define IMGST 4194304        // 64*65536
#define NB    4

// ================= K1: depthwise conv (unchanged) =================
__global__ __launch_bounds__(256) void dsattn_dwconv(
        const float* __restrict__ in, float* __restrict__ outp,
        const float* __restrict__ w3, const float* __restrict__ w5,
        const float* __restrict__ w7) {
    __shared__ float sm[38 * 38];
    __shared__ float wsm[49];
    const int tid = threadIdx.x;
    const int tile = blockIdx.x;
    const int tx = tile & 7, ty = tile >> 3;
    const int bc = blockIdx.y;            // b*64 + c
    const int c = bc & 63;
    const float* plane = in + (size_t)bc * NPX;
    const int row0 = ty * 32 - 3, col0 = tx * 32 - 3;

    for (int idx = tid; idx < 38 * 38; idx += 256) {
        int r = idx / 38, cc = idx - r * 38;
        int gr = row0 + r, gc = col0 + cc;
        float v = 0.f;
        if ((unsigned)gr < 256u && (unsigned)gc < 256u) v = plane[gr * 256 + gc];
        sm[idx] = v;
    }
    int k; const float* wp;
    if (c < 32)      { k = 3; wp = w3 + c * 9; }
    else if (c < 48) { k = 5; wp = w5 + (c - 32) * 25; }
    else             { k = 7; wp = w7 + (c - 48) * 49; }
    if (tid < k * k) wsm[tid] = wp[tid];
    __syncthreads();

    const int lx = tid & 31, ly0 = tid >> 5;
    float* oplane = outp + (size_t)bc * NPX;
#pragma unroll
    for (int rr = 0; rr < 4; ++rr) {
        const int ly = ly0 + rr * 8;
        float acc = 0.f;
        if (k == 3) {
#pragma unroll
            for (int dy = 0; dy < 3; ++dy)
#pragma unroll
                for (int dx = 0; dx < 3; ++dx)
                    acc = fmaf(wsm[dy * 3 + dx], sm[(ly + 2 + dy) * 38 + lx + 2 + dx], acc);
        } else if (k == 5) {
#pragma unroll
            for (int dy = 0; dy < 5; ++dy)
#pragma unroll
                for (int dx = 0; dx < 5; ++dx)
                    acc = fmaf(wsm[dy * 5 + dx], sm[(ly + 1 + dy) * 38 + lx + 1 + dx], acc);
        } else {
#pragma unroll
            for (int dy = 0; dy < 7; ++dy)
#pragma unroll
                for (int dx = 0; dx < 7; ++dx)
                    acc = fmaf(wsm[dy * 7 + dx], sm[(ly + dy) * 38 + lx + dx], acc);
        }
        oplane[(ty * 32 + ly) * 256 + tx * 32 + lx] = acc;
    }
}

// ================= K2: cross-Gram S_b = xh @ yh^T, K-split partials =================
__global__ __launch_bounds__(256) void dsattn_crossgram(
        const float* __restrict__ xh, const float* __restrict__ yh,
        float* __restrict__ Spart) {
    __shared__ float sx[64 * 65];
    __shared__ float sy[64 * 65];
    const int tid = threadIdx.x;
    const int chunk = blockIdx.x;
    const int b = blockIdx.y;
    const int rt = tid >> 4;      // 0..15
    const int ct = tid & 15;      // 0..15
    float acc[16];
#pragma unroll
    for (int i = 0; i < 16; ++i) acc[i] = 0.f;
    const size_t ibase = (size_t)b * IMGST + chunk * 512;

    for (int tile = 0; tile < 8; ++tile) {
        __syncthreads();
        for (int idx = tid; idx < 4096; idx += 256) {
            const int c = idx >> 6, p = idx & 63;
            const size_t g = ibase + (size_t)c * NPX + tile * 64 + p;
            sx[p * 65 + c] = xh[g];
            sy[p * 65 + c] = yh[g];
        }
        __syncthreads();
        for (int p = 0; p < 64; ++p) {
            float xr[4], yc[4];
#pragma unroll
            for (int j = 0; j < 4; ++j) {
                xr[j] = sx[p * 65 + rt * 4 + j];
                yc[j] = sy[p * 65 + ct * 4 + j];
            }
#pragma unroll
            for (int r = 0; r < 4; ++r)
#pragma unroll
                for (int c2 = 0; c2 < 4; ++c2)
                    acc[r * 4 + c2] = fmaf(xr[r], yc[c2], acc[r * 4 + c2]);
        }
    }
    float* outp = Spart + ((size_t)b * 128 + chunk) * 4096;
#pragma unroll
    for (int r = 0; r < 4; ++r)
#pragma unroll
        for (int c2 = 0; c2 < 4; ++c2)
            outp[(rt * 4 + r) * 64 + ct * 4 + c2] = acc[r * 4 + c2];
}

// ================= K2b: reduce S partials -> Sred[4][4096] =================
__global__ __launch_bounds__(256) void dsattn_reduceS(
        const float* __restrict__ Spart, float* __restrict__ Sred) {
    const int i = blockIdx.x * 256 + threadIdx.x;   // 0..4095
    const int b = blockIdx.y;
    const float* p = Spart + (size_t)b * 128 * 4096 + i;
    float s = 0.f;
#pragma unroll 4
    for (int k = 0; k < 128; ++k) s += p[(size_t)k * 4096];
    Sred[b * 4096 + i] = s;
}

// ================= K4: pooled Grams (Sxy, Sxx, Syy), K-split partials =================
__global__ __launch_bounds__(256) void dsattn_poolgram(
        const float* __restrict__ x, const float* __restrict__ y,
        float* __restrict__ Ppart) {
    __shared__ float sx[64 * 65];
    __shared__ float sy[64 * 65];
    const int tid = threadIdx.x;
    const int irow = blockIdx.x;   // pooled row
    const int b = blockIdx.y;
    const int rt = tid >> 4, ct = tid & 15;
    float aXY[16], aXX[16], aYY[16];
#pragma unroll
    for (int i = 0; i < 16; ++i) { aXY[i] = 0.f; aXX[i] = 0.f; aYY[i] = 0.f; }
    const size_t ibase = (size_t)b * IMGST + (size_t)(2 * irow) * 256;

    for (int tile = 0; tile < 2; ++tile) {
        __syncthreads();
        for (int idx = tid; idx < 4096; idx += 256) {
            const int c = idx >> 6, jj = idx & 63;
            const size_t g = ibase + (size_t)c * NPX + 2 * (tile * 64 + jj);
            const float* px0 = x + g;
            const float* py0 = y + g;
            sx[jj * 65 + c] = 0.25f * (px0[0] + px0[1] + px0[256] + px0[257]);
            sy[jj * 65 + c] = 0.25f * (py0[0] + py0[1] + py0[256] + py0[257]);
        }
        __syncthreads();
        for (int p = 0; p < 64; ++p) {
            float xr[4], xc[4], yr[4], yc[4];
#pragma unroll
            for (int j = 0; j < 4; ++j) {
                xr[j] = sx[p * 65 + rt * 4 + j];
                xc[j] = sx[p * 65 + ct * 4 + j];
                yr[j] = sy[p * 65 + rt * 4 + j];
                yc[j] = sy[p * 65 + ct * 4 + j];
            }
#pragma unroll
            for (int r = 0; r < 4; ++r)
#pragma unroll
                for (int c2 = 0; c2 < 4; ++c2) {
                    aXY[r * 4 + c2] = fmaf(xr[r], yc[c2], aXY[r * 4 + c2]);
                    aXX[r * 4 + c2] = fmaf(xr[r], xc[c2], aXX[r * 4 + c2]);
                    aYY[r * 4 + c2] = fmaf(yr[r], yc[c2], aYY[r * 4 + c2]);
                }
        }
    }
    float* outp = Ppart + ((size_t)b * 128 + irow) * 12288;
#pragma unroll
    for (int r = 0; r < 4; ++r)
#pragma unroll
        for (int c2 = 0; c2 < 4; ++c2) {
            const int o = (rt * 4 + r) * 64 + ct * 4 + c2;
            outp[o]        = aXY[r * 4 + c2];
            outp[4096 + o] = aXX[r * 4 + c2];
            outp[8192 + o] = aYY[r * 4 + c2];
        }
}

// ================= K4b: reduce P partials -> Pred[4][12288] =================
__global__ __launch_bounds__(256) void dsattn_reduceP(
        const float* __restrict__ Ppart, float* __restrict__ Pred) {
    const int i = blockIdx.x * 256 + threadIdx.x;   // 0..12287
    const int b = blockIdx.y;
    const float* p = Ppart + (size_t)b * 128 * 12288 + i;
    float s = 0.f;
#pragma unroll 4
    for (int k = 0; k < 128; ++k) s += p[(size_t)k * 12288];
    Pred[b * 12288 + i] = s;
}

// ================= K_A: sandwich products, grid (4 units, 4 img) =================
// unit 0: nq2 = diag(Wql Sxx Wql^T); unit 1: nk2 = diag(Wkl Syy Wkl^T)
// unit 2: G   = blockdiag8(Wql Sxy Wkl^T); unit 3: pooled = diag(Wq Sred Wk^T)/NPX
__global__ __launch_bounds__(256) void dsattn_sandwich(
        const float* __restrict__ Pred, const float* __restrict__ Sred,
        const float* __restrict__ wql, const float* __restrict__ wkl,
        const float* __restrict__ wq,  const float* __restrict__ wk,
        float* __restrict__ nq2g, float* __restrict__ nk2g,
        float* __restrict__ Gg, float* __restrict__ pooledg) {
    __shared__ float Wl[64 * 65];
    __shared__ float Sl[64 * 65];
    __shared__ float Tl[64 * 65];
    __shared__ float red[256];
    const int unit = blockIdx.x, b = blockIdx.y, tid = threadIdx.x;
    const float *W1, *W2, *Sg;
    if (unit == 0)      { W1 = wql; W2 = wql; Sg = Pred + (size_t)b * 12288 + 4096; }
    else if (unit == 1) { W1 = wkl; W2 = wkl; Sg = Pred + (size_t)b * 12288 + 8192; }
    else if (unit == 2) { W1 = wql; W2 = wkl; Sg = Pred + (size_t)b * 12288; }
    else                { W1 = wq;  W2 = wk;  Sg = Sred + (size_t)b * 4096; }

    for (int i = tid; i < 4096; i += 256) {
        const int r = i >> 6, c = i & 63;
        Wl[r * 65 + c] = W1[i];
        Sl[r * 65 + c] = Sg[i];
    }
    __syncthreads();

    // T = W1 @ S : thread (rt,ct) -> rows 4rt.., cols 4ct..
    const int rt = tid >> 4, ct = tid & 15;
    float acc[16];
#pragma unroll
    for (int i = 0; i < 16; ++i) acc[i] = 0.f;
    for (int cc = 0; cc < 64; ++cc) {
        float wr[4], sc[4];
#pragma unroll
        for (int j = 0; j < 4; ++j) {
            wr[j] = Wl[(rt * 4 + j) * 65 + cc];
            sc[j] = Sl[cc * 65 + ct * 4 + j];
        }
#pragma unroll
        for (int r = 0; r < 4; ++r)
#pragma unroll
            for (int c2 = 0; c2 < 4; ++c2)
                acc[r * 4 + c2] = fmaf(wr[r], sc[c2], acc[r * 4 + c2]);
    }
#pragma unroll
    for (int r = 0; r < 4; ++r)
#pragma unroll
        for (int c2 = 0; c2 < 4; ++c2)
            Tl[(rt * 4 + r) * 65 + ct * 4 + c2] = acc[r * 4 + c2];
    __syncthreads();
    // overwrite Sl with W2 (row-major, pad 65)
    for (int i = tid; i < 4096; i += 256) Sl[(i >> 6) * 65 + (i & 63)] = W2[i];
    __syncthreads();

    if (unit == 2) {
        // G[h,r,d] = sum_c T[h8+r,c] * W2[h8+d,c]
        for (int i = tid; i < 512; i += 256) {
            const int h = i >> 6, r = (i >> 3) & 7, d = i & 7;
            float s = 0.f;
#pragma unroll
            for (int c = 0; c < 64; ++c)
                s = fmaf(Tl[(h * 8 + r) * 65 + c], Sl[(h * 8 + d) * 65 + c], s);
            Gg[b * 512 + i] = s;
        }
    } else {
        // diag(T @ W2^T): row r, 4-way split over cp
        const int r = tid >> 2, part = tid & 3;
        float s = 0.f;
#pragma unroll
        for (int q = 0; q < 16; ++q) {
            const int cp = part * 16 + q;
            s = fmaf(Tl[r * 65 + cp], Sl[r * 65 + cp], s);
        }
        red[tid] = s;
        __syncthreads();
        if (tid < 64) {
            const float v = red[tid * 4] + red[tid * 4 + 1] + red[tid * 4 + 2] + red[tid * 4 + 3];
            if (unit == 0)      nq2g[b * 64 + tid] = v;
            else if (unit == 1) nk2g[b * 64 + tid] = v;
            else                pooledg[b * 64 + tid] = v * (1.f / 65536.f);
        }
    }
}

// ================= K_B: MLP + softmax + tvl, grid 4 =================
__global__ __launch_bounds__(256) void dsattn_smallmid(
        const float* __restrict__ nq2g, const float* __restrict__ nk2g,
        const float* __restrict__ Gg, const float* __restrict__ pooledg,
        const float* __restrict__ temp, const float* __restrict__ w1,
        const float* __restrict__ w2, const float* __restrict__ wvl,
        float* __restrict__ hattg, float* __restrict__ tvlg) {
    __shared__ float att[512];
    __shared__ float z[16];
    const int b = blockIdx.x, tid = threadIdx.x;
    if (tid < 16) {
        float a = 0.f;
#pragma unroll
        for (int c = 0; c < 64; ++c) a = fmaf(w1[tid * 64 + c], pooledg[b * 64 + c], a);
        z[tid] = fmaxf(a, 0.f);
    }
    if (tid < 64) {
        const int h = tid >> 3;
        const float tpr = temp[h];
        const float nq = fmaxf(sqrtf(nq2g[b * 64 + tid]), 1e-12f);
        float a[8], m = -1e30f;
#pragma unroll
        for (int d = 0; d < 8; ++d) {
            const float nk = fmaxf(sqrtf(nk2g[b * 64 + h * 8 + d]), 1e-12f);
            a[d] = Gg[b * 512 + tid * 8 + d] / (nq * nk) * tpr;
            m = fmaxf(m, a[d]);
        }
        float ssum = 0.f;
#pragma unroll
        for (int d = 0; d < 8; ++d) { a[d] = expf(a[d] - m); ssum += a[d]; }
        const float inv = 1.f / ssum;
#pragma unroll
        for (int d = 0; d < 8; ++d) att[tid * 8 + d] = a[d] * inv;
    }
    __syncthreads();
    if (tid < 64) {
        float a = 0.f;
#pragma unroll
        for (int i = 0; i < 16; ++i) a = fmaf(w2[tid * 16 + i], z[i], a);
        hattg[b * 64 + tid] = tanhf(a);
    }
    // tvl[m][c] = sum_d att[m,d] * wvl[h8+d, c]
    for (int i = tid; i < 4096; i += 256) {
        const int m = i >> 6, c = i & 63, h = m >> 3;
        float s = 0.f;
#pragma unroll
        for (int d = 0; d < 8; ++d) s = fmaf(att[m * 8 + d], wvl[(h * 8 + d) * 64 + c], s);
        tvlg[b * 4096 + i] = s;
    }
}

// ================= K_C: fold -> At, Bt; grid (2 units, 4 img) =================
// unit 0: At[c,o] = sum_m wproj[o,m]*hatt[m]*wvh[m,c]
// unit 1: Bt[c,o] = sum_m wproj[o,m]*tvl[m,c]
__global__ __launch_bounds__(256) void dsattn_fold(
        const float* __restrict__ wproj, const float* __restrict__ wvh,
        const float* __restrict__ hattg, const float* __restrict__ tvlg,
        float* __restrict__ At, float* __restrict__ Bt) {
    __shared__ float Pl[64 * 65];   // [o][m]
    __shared__ float Vl[64 * 65];   // [m][c]
    __shared__ float hm[64];
    const int unit = blockIdx.x, b = blockIdx.y, tid = threadIdx.x;
    if (tid < 64) hm[tid] = hattg[b * 64 + tid];
    for (int i = tid; i < 4096; i += 256) Pl[(i >> 6) * 65 + (i & 63)] = wproj[i];
    __syncthreads();
    for (int i = tid; i < 4096; i += 256) {
        const int m = i >> 6, c = i & 63;
        Vl[m * 65 + c] = (unit == 0) ? hm[m] * wvh[i] : tvlg[b * 4096 + i];
    }
    __syncthreads();

    const int rt = tid >> 4, ct = tid & 15;  // rt: c rows, ct: o cols
    float acc[16];
#pragma unroll
    for (int i = 0; i < 16; ++i) acc[i] = 0.f;
    for (int m = 0; m < 64; ++m) {
        float pv[4], vv[4];
#pragma unroll
        for (int j = 0; j < 4; ++j) {
            pv[j] = Pl[(ct * 4 + j) * 65 + m];
            vv[j] = Vl[m * 65 + rt * 4 + j];
        }
#pragma unroll
        for (int r = 0; r < 4; ++r)
#pragma unroll
            for (int c2 = 0; c2 < 4; ++c2)
                acc[r * 4 + c2] = fmaf(pv[c2], vv[r], acc[r * 4 + c2]);
    }
    float* outp = ((unit == 0) ? At : Bt) + (size_t)b * 4096;
#pragma unroll
    for (int r = 0; r < 4; ++r)
#pragma unroll
        for (int c2 = 0; c2 < 4; ++c2)
            outp[(rt * 4 + r) * 64 + ct * 4 + c2] = acc[r * 4 + c2];
}

// ================= K6: out = A_b @ xh + B_b @ y  (tiled, LDS, acc[16]) =================
__global__ __launch_bounds__(256) void dsattn_final(
        const float* __restrict__ xh, const float* __restrict__ y,
        const float* __restrict__ At, const float* __restrict__ Bt,
        float* __restrict__ out) {
    __shared__ float Al[4096];   // [c][o]
    __shared__ float Bl[4096];
    __shared__ float xs[4096];   // [c][p]
    __shared__ float ys[4096];
    const int tid = threadIdx.x;
    const int b = blockIdx.y;                 // wave-uniform image index
    const size_t base = (size_t)b * IMGST + (size_t)blockIdx.x * 64;

    for (int i = tid; i < 4096; i += 256) {
        Al[i] = At[b * 4096 + i];
        Bl[i] = Bt[b * 4096 + i];
        const int c = i >> 6, p = i & 63;
        const size_t g = base + (size_t)c * NPX + p;
        xs[i] = xh[g];
        ys[i] = y[g];
    }
    __syncthreads();

    const int p  = tid & 63;
    const int ob = (tid >> 6) * 16;
    float acc[16];
#pragma unroll
    for (int o = 0; o < 16; ++o) acc[o] = 0.f;

#pragma unroll 4
    for (int c = 0; c < 64; ++c) {
        const float xv = xs[c * 64 + p];
        const float yv = ys[c * 64 + p];
        const float4* Ar = reinterpret_cast<const float4*>(&Al[c * 64 + ob]);
        const float4* Br = reinterpret_cast<const float4*>(&Bl[c * 64 + ob]);
#pragma unroll
        for (int q = 0; q < 4; ++q) {
            const float4 a  = Ar[q];
            const float4 bb = Br[q];
            acc[q * 4 + 0] = fmaf(a.x, xv, acc[q * 4 + 0]);
            acc[q * 4 + 1] = fmaf(a.y, xv, acc[q * 4 + 1]);
            acc[q * 4 + 2] = fmaf(a.z, xv, acc[q * 4 + 2]);
            acc[q * 4 + 3] = fmaf(a.w, xv, acc[q * 4 + 3]);
            acc[q * 4 + 0] = fmaf(bb.x, yv, acc[q * 4 + 0]);
            acc[q * 4 + 1] = fmaf(bb.y, yv, acc[q * 4 + 1]);
            acc[q * 4 + 2] = fmaf(bb.z, yv, acc[q * 4 + 2]);
            acc[q * 4 + 3] = fmaf(bb.w, yv, acc[q * 4 + 3]);
        }
    }

    float* op = out + base;
#pragma unroll
    for (int o = 0; o < 16; ++o)
        op[(size_t)(ob + o) * NPX + p] = acc[o];
}

// ================= launch =================
extern "C" void kernel_launch(void* const* d_in, const int* in_sizes, int n_in,
                              void* d_out, int out_size, void* d_ws, size_t ws_size,
                              hipStream_t stream) {
    const float* x      = (const float*)d_in[0];
    const float* y      = (const float*)d_in[1];
    const float* hp1_w3 = (const float*)d_in[2];
    const float* hp1_w5 = (const float*)d_in[3];
    const float* hp1_w7 = (const float*)d_in[4];
    const float* hp2_w3 = (const float*)d_in[5];
    const float* hp2_w5 = (const float*)d_in[6];
    const float* hp2_w7 = (const float*)d_in[7];
    const float* qh_w   = (const float*)d_in[8];
    const float* kh_w   = (const float*)d_in[9];
    const float* vh_w   = (const float*)d_in[10];
    const float* ql_w   = (const float*)d_in[11];
    const float* kl_w   = (const float*)d_in[12];
    const float* vl_w   = (const float*)d_in[13];
    const float* proj_w = (const float*)d_in[14];
    const float* attn_w1 = (const float*)d_in[15];
    const float* attn_w2 = (const float*)d_in[16];
    const float* temperature = (const float*)d_in[17];

    float* out = (float*)d_out;

    // ws layout (floats):
    float* xh     = (float*)d_ws;                    // 16,777,216
    float* Spart  = xh + (size_t)NB * IMGST;         // 2,097,152
    float* small  = Spart + (size_t)4 * 128 * 4096;
    float* Sred   = small;                           // 16,384
    float* Pred   = Sred + 16384;                    // 49,152
    float* nq2    = Pred + 49152;                    // 256
    float* nk2    = nq2 + 256;                       // 256
    float* G      = nk2 + 256;                       // 2,048
    float* pooled = G + 2048;                        // 256
    float* hatt   = pooled + 256;                    // 256
    float* tvl    = hatt + 256;                      // 16,384
    float* At     = tvl + 16384;                     // 16,384
    float* Bt     = At + 16384;                      // 16,384

    float* yh    = out;                              // d_out scratch until crossgram done
    float* Ppart = out;                              // d_out scratch after crossgram

    dsattn_dwconv<<<dim3(64, 256), 256, 0, stream>>>(x, xh, hp1_w3, hp1_w5, hp1_w7);
    dsattn_dwconv<<<dim3(64, 256), 256, 0, stream>>>(y, yh, hp2_w3, hp2_w5, hp2_w7);
    dsattn_crossgram<<<dim3(128, 4), 256, 0, stream>>>(xh, yh, Spart);
    dsattn_reduceS<<<dim3(16, 4), 256, 0, stream>>>(Spart, Sred);
    dsattn_poolgram<<<dim3(128, 4), 256, 0, stream>>>(x, y, Ppart);
    dsattn_reduceP<<<dim3(48, 4), 256, 0, stream>>>(Ppart, Pred);
    dsattn_sandwich<<<dim3(4, 4), 256, 0, stream>>>(Pred, Sred, ql_w, kl_w, qh_w, kh_w,
                                                    nq2, nk2, G, pooled);
    dsattn_smallmid<<<4, 256, 0, stream>>>(nq2, nk2, G, pooled, temperature,
                                           attn_w1, attn_w2, vl_w, hatt, tvl);
    dsattn_fold<<<dim3(2, 4), 256, 0, stream>>>(proj_w, vh_w, hatt, tvl, At, Bt);
    dsattn_final<<<dim3(1024, 4), 256, 0, stream>>>(xh, y, At, Bt, out);
}